// Round 4
// baseline (715.533 us; speedup 1.0000x reference)
//
#include <hip/hip_runtime.h>
#include <math.h>

#define DIM  64
#define SPAN 256      // nodes per coarse bucket; LDS accumulator = SPAN*DIM*4B = 64 KB
#define NBIN 128      // binning blocks (count matrix = K*NBIN, private payload segments)
#define KMAX 512      // max buckets supported (N <= 131072)

// ---------------- Kernel 1: per-node scores --------------------------------
__global__ void score_kernel(const float* __restrict__ x,
                             const float* __restrict__ w_src,
                             const float* __restrict__ w_dst,
                             float* __restrict__ a_src,
                             float* __restrict__ a_dst,
                             int N) {
    int gid  = blockIdx.x * blockDim.x + threadIdx.x;
    int node = gid >> 6;
    int lane = threadIdx.x & 63;
    if (node >= N) return;
    float xv = x[(size_t)node * DIM + lane];
    float s1 = xv * w_src[lane];
    float s2 = xv * w_dst[lane];
    #pragma unroll
    for (int off = 32; off > 0; off >>= 1) {
        s1 += __shfl_down(s1, off, 64);
        s2 += __shfl_down(s2, off, 64);
    }
    if (lane == 0) {
        a_src[node] = s1;
        a_dst[node] = s2;
    }
}

// ---------------- Kernel 2: coarse histogram (deterministic matrix) --------
// cnt[bucket * NBIN + block] = #edges of `bucket` seen by `block`.
__global__ void hist_coarse(const int* __restrict__ dst, int* __restrict__ cnt,
                            int E, int N, int K) {
    __shared__ int lh[KMAX];
    int tid = threadIdx.x;
    for (int j = tid; j < K; j += blockDim.x) lh[j] = 0;
    __syncthreads();
    for (int base = blockIdx.x * 256; base < E; base += NBIN * 256) {
        int e = base + tid;
        if (e < E) {
            unsigned t = (unsigned)dst[e];
            if (t >= (unsigned)N) t = 0;          // guard
            atomicAdd(&lh[t >> 8], 1);            // SPAN=256 -> bucket = t>>8
        }
    }
    __syncthreads();
    for (int j = tid; j < K; j += blockDim.x)
        cnt[j * NBIN + blockIdx.x] = lh[j];
}

// ---------------- Kernels 3-5: exclusive scan (double-buffered HS) ---------
__global__ void scan_part(const int* __restrict__ cnt, int* __restrict__ offs,
                          int* __restrict__ bsum, int N) {
    __shared__ int buf[2][256];
    int tid = threadIdx.x;
    int i = blockIdx.x * 256 + tid;
    int v = (i < N) ? cnt[i] : 0;
    int sel = 0;
    buf[0][tid] = v;
    __syncthreads();
    for (int off = 1; off < 256; off <<= 1) {
        int nsel = sel ^ 1;
        buf[nsel][tid] = buf[sel][tid] + ((tid >= off) ? buf[sel][tid - off] : 0);
        __syncthreads();
        sel = nsel;
    }
    if (i < N) offs[i] = buf[sel][tid] - v;
    if (tid == 255) bsum[blockIdx.x] = buf[sel][255];
}

__global__ void scan_top(int* __restrict__ bsum, int* __restrict__ offs,
                         int NB, int N) {
    __shared__ int buf[2][512];
    int tid = threadIdx.x;
    int v = (tid < NB) ? bsum[tid] : 0;
    int sel = 0;
    buf[0][tid] = v;
    __syncthreads();
    for (int off = 1; off < 512; off <<= 1) {
        int nsel = sel ^ 1;
        buf[nsel][tid] = buf[sel][tid] + ((tid >= off) ? buf[sel][tid - off] : 0);
        __syncthreads();
        sel = nsel;
    }
    if (tid < NB) bsum[tid] = buf[sel][tid] - v;
    if (tid == 511) offs[N] = buf[sel][511];      // grand total = E
}

__global__ void scan_add(int* __restrict__ offs, const int* __restrict__ bsum,
                         int N) {
    int i = blockIdx.x * 256 + threadIdx.x;
    if (i < N) offs[i] += bsum[blockIdx.x];
}

// ---------------- Kernel 6: partition edges into coarse buckets ------------
// Each block appends into its PRIVATE segment per bucket (offs[bucket*NBIN+blk])
// via block-local LDS cursors -> no global atomics, no cross-XCD line sharing.
__global__ void binpass_kernel(const float* __restrict__ ew,
                               const int* __restrict__ src_idx,
                               const int* __restrict__ dst_idx,
                               const float* __restrict__ a_src,
                               const float* __restrict__ a_dst,
                               const int* __restrict__ offs,
                               unsigned* __restrict__ rec,
                               float* __restrict__ pa,
                               int E, int N, int K) {
    __shared__ int lcur[KMAX];
    int tid = threadIdx.x;
    for (int j = tid; j < K; j += blockDim.x)
        lcur[j] = offs[j * NBIN + blockIdx.x];
    __syncthreads();
    for (int base = blockIdx.x * 256; base < E; base += NBIN * 256) {
        int e = base + tid;
        if (e < E) {
            unsigned s = (unsigned)src_idx[e];
            unsigned t = (unsigned)dst_idx[e];
            if (s >= (unsigned)N) s = 0;          // guard
            if (t >= (unsigned)N) t = 0;          // guard
            float a = tanhf(a_src[s] + a_dst[t]) * ew[e];
            int bk = (int)(t >> 8);
            int pos = atomicAdd(&lcur[bk], 1);    // LDS atomic, block-local
            rec[pos] = (s << 8) | (t & 255u);     // src(24b) | dst_local(8b)
            pa[pos]  = a;
        }
    }
}

// ---------------- Kernel 7: per-bucket LDS accumulate ----------------------
// One block per bucket. hacc[SPAN][DIM] in LDS; 16 waves, 4-deep unroll;
// lane = dim -> ds_add_f32 with 2-way bank aliasing (free). Single h write.
__global__ __launch_bounds__(1024) void accumulate_kernel(
        const float* __restrict__ x,
        const unsigned* __restrict__ rec,
        const float* __restrict__ pa,
        const int* __restrict__ offs,
        float* __restrict__ h,
        int N) {
    __shared__ float hacc[SPAN * DIM];            // 64 KB
    int tid  = threadIdx.x;
    int lane = tid & 63;
    int wave = tid >> 6;
    const int NW = blockDim.x >> 6;               // 16 waves
    int b = blockIdx.x;
    for (int j = tid; j < SPAN * DIM; j += blockDim.x) hacc[j] = 0.f;
    __syncthreads();
    int p   = offs[b * NBIN] + wave;
    int end = offs[(b + 1) * NBIN];               // b=K-1 -> offs[Ntot] = E
    for (; p + 3 * NW < end; p += 4 * NW) {
        unsigned r0 = rec[p];
        unsigned r1 = rec[p + NW];
        unsigned r2 = rec[p + 2 * NW];
        unsigned r3 = rec[p + 3 * NW];
        float a0 = pa[p];
        float a1 = pa[p + NW];
        float a2 = pa[p + 2 * NW];
        float a3 = pa[p + 3 * NW];
        float x0 = x[(size_t)(r0 >> 8) * DIM + lane];
        float x1 = x[(size_t)(r1 >> 8) * DIM + lane];
        float x2 = x[(size_t)(r2 >> 8) * DIM + lane];
        float x3 = x[(size_t)(r3 >> 8) * DIM + lane];
        atomicAdd(&hacc[(r0 & 255u) * DIM + lane], a0 * x0);
        atomicAdd(&hacc[(r1 & 255u) * DIM + lane], a1 * x1);
        atomicAdd(&hacc[(r2 & 255u) * DIM + lane], a2 * x2);
        atomicAdd(&hacc[(r3 & 255u) * DIM + lane], a3 * x3);
    }
    for (; p < end; p += NW) {
        unsigned r = rec[p];
        float a = pa[p];
        atomicAdd(&hacc[(r & 255u) * DIM + lane],
                  a * x[(size_t)(r >> 8) * DIM + lane]);
    }
    __syncthreads();
    size_t nodebase = (size_t)b * SPAN;
    for (int j = tid; j < SPAN * DIM; j += blockDim.x) {
        size_t node = nodebase + (size_t)(j >> 6);
        if (node < (size_t)N) h[nodebase * DIM + j] = hacc[j];
    }
}

// ---------------- Fallback (round-1 atomic path, known-good) ---------------
__global__ void zero_out_kernel(float* __restrict__ p, int n) {
    int i = blockIdx.x * blockDim.x + threadIdx.x;
    if (i < n) p[i] = 0.f;
}

__global__ void edge_kernel_atomic(const float* __restrict__ x,
                                   const float* __restrict__ ew,
                                   const int* __restrict__ src_idx,
                                   const int* __restrict__ dst_idx,
                                   const float* __restrict__ a_src,
                                   const float* __restrict__ a_dst,
                                   float* __restrict__ h,
                                   int E) {
    int gid  = blockIdx.x * blockDim.x + threadIdx.x;
    int e    = gid >> 6;
    int lane = threadIdx.x & 63;
    if (e >= E) return;
    int s = src_idx[e];
    int t = dst_idx[e];
    float a  = tanhf(a_src[s] + a_dst[t]) * ew[e];
    float xv = x[(size_t)s * DIM + lane];
    atomicAdd(&h[(size_t)t * DIM + lane], a * xv);
}

extern "C" void kernel_launch(void* const* d_in, const int* in_sizes, int n_in,
                              void* d_out, int out_size, void* d_ws, size_t ws_size,
                              hipStream_t stream) {
    const float* x     = (const float*)d_in[0];
    const float* w_src = (const float*)d_in[1];
    const float* w_dst = (const float*)d_in[2];
    const float* ew    = (const float*)d_in[3];
    const int*   src   = (const int*)d_in[4];
    const int*   dst   = (const int*)d_in[5];
    float* h = (float*)d_out;

    int N = in_sizes[0] / DIM;
    int E = in_sizes[3];

    int K    = (N + SPAN - 1) / SPAN;     // coarse buckets
    int Ntot = K * NBIN;                  // count-matrix size
    int NBs  = (Ntot + 255) / 256;        // scan blocks

    // ws layout (4B units):
    // [a_src N][a_dst N][cnt Ntot][offs Ntot+1][bsum NBs][rec E][pa E]
    float*    a_src = (float*)d_ws;
    float*    a_dst = a_src + N;
    int*      cnt   = (int*)(a_dst + N);
    int*      offs  = cnt + Ntot;
    int*      bsum  = offs + Ntot + 1;
    unsigned* rec   = (unsigned*)(bsum + NBs);
    float*    pa    = (float*)(rec + E);
    size_t need = ((size_t)(2 * N) + 2 * (size_t)Ntot + 1 + NBs + 2 * (size_t)E) * 4;

    int score_blocks = (N + 3) / 4;       // one wave per node, 4 waves/block
    score_kernel<<<score_blocks, 256, 0, stream>>>(x, w_src, w_dst, a_src, a_dst, N);

    if (ws_size < need || K > KMAX || NBs > 512) {
        // fallback: round-1 atomic path
        int ob = (out_size + 255) / 256;
        zero_out_kernel<<<ob, 256, 0, stream>>>(h, out_size);
        int edge_blocks = (E + 3) / 4;
        edge_kernel_atomic<<<edge_blocks, 256, 0, stream>>>(x, ew, src, dst,
                                                            a_src, a_dst, h, E);
        return;
    }

    hist_coarse<<<NBIN, 256, 0, stream>>>(dst, cnt, E, N, K);
    scan_part<<<NBs, 256, 0, stream>>>(cnt, offs, bsum, Ntot);
    scan_top<<<1, 512, 0, stream>>>(bsum, offs, NBs, Ntot);
    scan_add<<<NBs, 256, 0, stream>>>(offs, bsum, Ntot);
    binpass_kernel<<<NBIN, 256, 0, stream>>>(ew, src, dst, a_src, a_dst,
                                             offs, rec, pa, E, N, K);
    accumulate_kernel<<<K, 1024, 0, stream>>>(x, rec, pa, offs, h, N);
}

// Round 5
// 282.877 us; speedup vs baseline: 2.5295x; 2.5295x over previous
//
#include <hip/hip_runtime.h>
#include <math.h>

#define DIM 64

// ---------------- Kernel 1: per-node scores --------------------------------
__global__ void score_kernel(const float* __restrict__ x,
                             const float* __restrict__ w_src,
                             const float* __restrict__ w_dst,
                             float* __restrict__ a_src,
                             float* __restrict__ a_dst,
                             int N) {
    int gid  = blockIdx.x * blockDim.x + threadIdx.x;
    int node = gid >> 6;
    int lane = threadIdx.x & 63;
    if (node >= N) return;
    float xv = x[(size_t)node * DIM + lane];
    float s1 = xv * w_src[lane];
    float s2 = xv * w_dst[lane];
    #pragma unroll
    for (int off = 32; off > 0; off >>= 1) {
        s1 += __shfl_down(s1, off, 64);
        s2 += __shfl_down(s2, off, 64);
    }
    if (lane == 0) {
        a_src[node] = s1;
        a_dst[node] = s2;
    }
}

// ---------------- zero the histogram (no memset inside capture) ------------
__global__ void zero_int_kernel(int* __restrict__ p, int n) {
    int i = blockIdx.x * blockDim.x + threadIdx.x;
    if (i < n) p[i] = 0;
}

// ---------------- Kernel 2: histogram of dst -------------------------------
__global__ void hist_kernel(const int* __restrict__ dst, int* __restrict__ cnt,
                            int E, int N) {
    int e = blockIdx.x * blockDim.x + threadIdx.x;
    if (e >= E) return;
    unsigned t = (unsigned)dst[e];
    if (t < (unsigned)N) atomicAdd(&cnt[t], 1);
}

// ---------------- Kernels 3-5: exclusive scan (double-buffered HS) ---------
__global__ void scan_part(const int* __restrict__ cnt, int* __restrict__ offs,
                          int* __restrict__ bsum, int N) {
    __shared__ int buf[2][256];
    int tid = threadIdx.x;
    int i = blockIdx.x * 256 + tid;
    int v = (i < N) ? cnt[i] : 0;
    int sel = 0;
    buf[0][tid] = v;
    __syncthreads();
    for (int off = 1; off < 256; off <<= 1) {
        int nsel = sel ^ 1;
        buf[nsel][tid] = buf[sel][tid] + ((tid >= off) ? buf[sel][tid - off] : 0);
        __syncthreads();
        sel = nsel;
    }
    if (i < N) offs[i] = buf[sel][tid] - v;
    if (tid == 255) bsum[blockIdx.x] = buf[sel][255];
}

__global__ void scan_top(int* __restrict__ bsum, int* __restrict__ offs,
                         int NB, int N) {
    __shared__ int buf[2][512];
    int tid = threadIdx.x;
    int v = (tid < NB) ? bsum[tid] : 0;
    int sel = 0;
    buf[0][tid] = v;
    __syncthreads();
    for (int off = 1; off < 512; off <<= 1) {
        int nsel = sel ^ 1;
        buf[nsel][tid] = buf[sel][tid] + ((tid >= off) ? buf[sel][tid - off] : 0);
        __syncthreads();
        sel = nsel;
    }
    if (tid < NB) bsum[tid] = buf[sel][tid] - v;
    if (tid == 511) offs[N] = buf[sel][511];      // grand total = E
}

__global__ void scan_add(int* __restrict__ offs, int* __restrict__ cursor,
                         const int* __restrict__ bsum, int N) {
    int i = blockIdx.x * 256 + threadIdx.x;
    if (i < N) {
        int o = offs[i] + bsum[blockIdx.x];
        offs[i] = o;
        cursor[i] = o;
    }
}

// ---------------- Kernel 6: scatter edges into dst-sorted order ------------
// Single 8B store per edge: pay[p] = src<<32 | float_bits(a)
__global__ void scatter_kernel(const float* __restrict__ ew,
                               const int* __restrict__ src_idx,
                               const int* __restrict__ dst_idx,
                               const float* __restrict__ a_src,
                               const float* __restrict__ a_dst,
                               int* __restrict__ cursor,
                               unsigned long long* __restrict__ pay,
                               int E, int N) {
    int e = blockIdx.x * blockDim.x + threadIdx.x;
    if (e >= E) return;
    unsigned s = (unsigned)src_idx[e];
    unsigned t = (unsigned)dst_idx[e];
    if (s >= (unsigned)N || t >= (unsigned)N) return;   // guard (no fault)
    float a = tanhf(a_src[s] + a_dst[t]) * ew[e];
    int p = atomicAdd(&cursor[t], 1);
    if ((unsigned)p < (unsigned)E)                      // guard (no fault)
        pay[p] = ((unsigned long long)s << 32) | (unsigned long long)__float_as_uint(a);
}

// ---------------- Kernel 7: gather per dst node, 8-deep batched ------------
// One wave per node. 8 uniform rec loads -> 8 independent x-row loads in
// flight -> 8 FMAs into 4 accumulators. MLP is the currency here.
__global__ void gather_kernel(const float* __restrict__ x,
                              const unsigned long long* __restrict__ pay,
                              const int* __restrict__ offs,
                              float* __restrict__ h,
                              int N, int E) {
    int gid  = blockIdx.x * blockDim.x + threadIdx.x;
    int t    = gid >> 6;
    int lane = threadIdx.x & 63;
    if (t >= N) return;
    int p   = offs[t];
    int end = offs[t + 1];
    if (p < 0) p = 0;
    if (end > E) end = E;
    float a0 = 0.f, a1 = 0.f, a2 = 0.f, a3 = 0.f;

    while (p + 8 <= end) {
        unsigned long long r0 = pay[p];
        unsigned long long r1 = pay[p + 1];
        unsigned long long r2 = pay[p + 2];
        unsigned long long r3 = pay[p + 3];
        unsigned long long r4 = pay[p + 4];
        unsigned long long r5 = pay[p + 5];
        unsigned long long r6 = pay[p + 6];
        unsigned long long r7 = pay[p + 7];
        p += 8;
        unsigned s0 = (unsigned)(r0 >> 32); if (s0 >= (unsigned)N) s0 = 0;
        unsigned s1 = (unsigned)(r1 >> 32); if (s1 >= (unsigned)N) s1 = 0;
        unsigned s2 = (unsigned)(r2 >> 32); if (s2 >= (unsigned)N) s2 = 0;
        unsigned s3 = (unsigned)(r3 >> 32); if (s3 >= (unsigned)N) s3 = 0;
        unsigned s4 = (unsigned)(r4 >> 32); if (s4 >= (unsigned)N) s4 = 0;
        unsigned s5 = (unsigned)(r5 >> 32); if (s5 >= (unsigned)N) s5 = 0;
        unsigned s6 = (unsigned)(r6 >> 32); if (s6 >= (unsigned)N) s6 = 0;
        unsigned s7 = (unsigned)(r7 >> 32); if (s7 >= (unsigned)N) s7 = 0;
        float x0 = x[(size_t)s0 * DIM + lane];
        float x1 = x[(size_t)s1 * DIM + lane];
        float x2 = x[(size_t)s2 * DIM + lane];
        float x3 = x[(size_t)s3 * DIM + lane];
        float x4 = x[(size_t)s4 * DIM + lane];
        float x5 = x[(size_t)s5 * DIM + lane];
        float x6 = x[(size_t)s6 * DIM + lane];
        float x7 = x[(size_t)s7 * DIM + lane];
        a0 = fmaf(__uint_as_float((unsigned)r0), x0, a0);
        a1 = fmaf(__uint_as_float((unsigned)r1), x1, a1);
        a2 = fmaf(__uint_as_float((unsigned)r2), x2, a2);
        a3 = fmaf(__uint_as_float((unsigned)r3), x3, a3);
        a0 = fmaf(__uint_as_float((unsigned)r4), x4, a0);
        a1 = fmaf(__uint_as_float((unsigned)r5), x5, a1);
        a2 = fmaf(__uint_as_float((unsigned)r6), x6, a2);
        a3 = fmaf(__uint_as_float((unsigned)r7), x7, a3);
    }
    if (p + 4 <= end) {
        unsigned long long r0 = pay[p];
        unsigned long long r1 = pay[p + 1];
        unsigned long long r2 = pay[p + 2];
        unsigned long long r3 = pay[p + 3];
        p += 4;
        unsigned s0 = (unsigned)(r0 >> 32); if (s0 >= (unsigned)N) s0 = 0;
        unsigned s1 = (unsigned)(r1 >> 32); if (s1 >= (unsigned)N) s1 = 0;
        unsigned s2 = (unsigned)(r2 >> 32); if (s2 >= (unsigned)N) s2 = 0;
        unsigned s3 = (unsigned)(r3 >> 32); if (s3 >= (unsigned)N) s3 = 0;
        float x0 = x[(size_t)s0 * DIM + lane];
        float x1 = x[(size_t)s1 * DIM + lane];
        float x2 = x[(size_t)s2 * DIM + lane];
        float x3 = x[(size_t)s3 * DIM + lane];
        a0 = fmaf(__uint_as_float((unsigned)r0), x0, a0);
        a1 = fmaf(__uint_as_float((unsigned)r1), x1, a1);
        a2 = fmaf(__uint_as_float((unsigned)r2), x2, a2);
        a3 = fmaf(__uint_as_float((unsigned)r3), x3, a3);
    }
    if (p + 2 <= end) {
        unsigned long long r0 = pay[p];
        unsigned long long r1 = pay[p + 1];
        p += 2;
        unsigned s0 = (unsigned)(r0 >> 32); if (s0 >= (unsigned)N) s0 = 0;
        unsigned s1 = (unsigned)(r1 >> 32); if (s1 >= (unsigned)N) s1 = 0;
        float x0 = x[(size_t)s0 * DIM + lane];
        float x1 = x[(size_t)s1 * DIM + lane];
        a0 = fmaf(__uint_as_float((unsigned)r0), x0, a0);
        a1 = fmaf(__uint_as_float((unsigned)r1), x1, a1);
    }
    if (p < end) {
        unsigned long long r0 = pay[p];
        unsigned s0 = (unsigned)(r0 >> 32); if (s0 >= (unsigned)N) s0 = 0;
        a0 = fmaf(__uint_as_float((unsigned)r0), x[(size_t)s0 * DIM + lane], a0);
    }
    h[(size_t)t * DIM + lane] = (a0 + a1) + (a2 + a3);
}

// ---------------- Fallback (round-1 atomic path, known-good) ---------------
__global__ void zero_out_kernel(float* __restrict__ p, int n) {
    int i = blockIdx.x * blockDim.x + threadIdx.x;
    if (i < n) p[i] = 0.f;
}

__global__ void edge_kernel_atomic(const float* __restrict__ x,
                                   const float* __restrict__ ew,
                                   const int* __restrict__ src_idx,
                                   const int* __restrict__ dst_idx,
                                   const float* __restrict__ a_src,
                                   const float* __restrict__ a_dst,
                                   float* __restrict__ h,
                                   int E) {
    int gid  = blockIdx.x * blockDim.x + threadIdx.x;
    int e    = gid >> 6;
    int lane = threadIdx.x & 63;
    if (e >= E) return;
    int s = src_idx[e];
    int t = dst_idx[e];
    float a  = tanhf(a_src[s] + a_dst[t]) * ew[e];
    float xv = x[(size_t)s * DIM + lane];
    atomicAdd(&h[(size_t)t * DIM + lane], a * xv);
}

extern "C" void kernel_launch(void* const* d_in, const int* in_sizes, int n_in,
                              void* d_out, int out_size, void* d_ws, size_t ws_size,
                              hipStream_t stream) {
    const float* x     = (const float*)d_in[0];
    const float* w_src = (const float*)d_in[1];
    const float* w_dst = (const float*)d_in[2];
    const float* ew    = (const float*)d_in[3];
    const int*   src   = (const int*)d_in[4];
    const int*   dst   = (const int*)d_in[5];
    float* h = (float*)d_out;

    int N = in_sizes[0] / DIM;
    int E = in_sizes[3];
    int NB = (N + 255) / 256;

    // ws layout (4B units):
    // [a_src N][a_dst N][cnt N][offs N+1][cursor N][bsum NB][pad->8B][pay E*8B]
    float* a_src  = (float*)d_ws;
    float* a_dst  = a_src + N;
    int*   cnt    = (int*)(a_dst + N);
    int*   offs   = cnt + N;
    int*   cursor = offs + N + 1;
    int*   bsum   = cursor + N;
    size_t head_bytes = ((size_t)(5 * N + 1 + NB)) * 4;
    size_t pay_off = (head_bytes + 15) & ~(size_t)15;
    unsigned long long* pay = (unsigned long long*)((char*)d_ws + pay_off);
    size_t need = pay_off + (size_t)E * 8;

    int score_blocks = (N + 3) / 4;
    score_kernel<<<score_blocks, 256, 0, stream>>>(x, w_src, w_dst, a_src, a_dst, N);

    if (ws_size < need || NB > 512) {
        // fallback: round-1 atomic path
        int ob = (out_size + 255) / 256;
        zero_out_kernel<<<ob, 256, 0, stream>>>(h, out_size);
        int edge_blocks = (E + 3) / 4;
        edge_kernel_atomic<<<edge_blocks, 256, 0, stream>>>(x, ew, src, dst,
                                                            a_src, a_dst, h, E);
        return;
    }

    zero_int_kernel<<<NB, 256, 0, stream>>>(cnt, N);
    int eb = (E + 255) / 256;
    hist_kernel<<<eb, 256, 0, stream>>>(dst, cnt, E, N);
    scan_part<<<NB, 256, 0, stream>>>(cnt, offs, bsum, N);
    scan_top<<<1, 512, 0, stream>>>(bsum, offs, NB, N);
    scan_add<<<NB, 256, 0, stream>>>(offs, cursor, bsum, N);
    scatter_kernel<<<eb, 256, 0, stream>>>(ew, src, dst, a_src, a_dst,
                                           cursor, pay, E, N);
    int gather_blocks = (N + 3) / 4;
    gather_kernel<<<gather_blocks, 256, 0, stream>>>(x, pay, offs, h, N, E);
}

// Round 6
// 270.859 us; speedup vs baseline: 2.6417x; 1.0444x over previous
//
#include <hip/hip_runtime.h>
#include <math.h>

#define DIM 64

// ---------------- Kernel 1: per-node scores --------------------------------
__global__ void score_kernel(const float* __restrict__ x,
                             const float* __restrict__ w_src,
                             const float* __restrict__ w_dst,
                             float* __restrict__ a_src,
                             float* __restrict__ a_dst,
                             int N) {
    int gid  = blockIdx.x * blockDim.x + threadIdx.x;
    int node = gid >> 6;
    int lane = threadIdx.x & 63;
    if (node >= N) return;
    float xv = x[(size_t)node * DIM + lane];
    float s1 = xv * w_src[lane];
    float s2 = xv * w_dst[lane];
    #pragma unroll
    for (int off = 32; off > 0; off >>= 1) {
        s1 += __shfl_down(s1, off, 64);
        s2 += __shfl_down(s2, off, 64);
    }
    if (lane == 0) {
        a_src[node] = s1;
        a_dst[node] = s2;
    }
}

// ---------------- zero the histogram (no memset inside capture) ------------
__global__ void zero_int_kernel(int* __restrict__ p, int n) {
    int i = blockIdx.x * blockDim.x + threadIdx.x;
    if (i < n) p[i] = 0;
}

// ---------------- Kernel 2: histogram of dst -------------------------------
__global__ void hist_kernel(const int* __restrict__ dst, int* __restrict__ cnt,
                            int E, int N) {
    int e = blockIdx.x * blockDim.x + threadIdx.x;
    if (e >= E) return;
    unsigned t = (unsigned)dst[e];
    if (t < (unsigned)N) atomicAdd(&cnt[t], 1);
}

// ---------------- Kernels 3-5: exclusive scan (double-buffered HS) ---------
__global__ void scan_part(const int* __restrict__ cnt, int* __restrict__ offs,
                          int* __restrict__ bsum, int N) {
    __shared__ int buf[2][256];
    int tid = threadIdx.x;
    int i = blockIdx.x * 256 + tid;
    int v = (i < N) ? cnt[i] : 0;
    int sel = 0;
    buf[0][tid] = v;
    __syncthreads();
    for (int off = 1; off < 256; off <<= 1) {
        int nsel = sel ^ 1;
        buf[nsel][tid] = buf[sel][tid] + ((tid >= off) ? buf[sel][tid - off] : 0);
        __syncthreads();
        sel = nsel;
    }
    if (i < N) offs[i] = buf[sel][tid] - v;
    if (tid == 255) bsum[blockIdx.x] = buf[sel][255];
}

__global__ void scan_top(int* __restrict__ bsum, int* __restrict__ offs,
                         int NB, int N) {
    __shared__ int buf[2][512];
    int tid = threadIdx.x;
    int v = (tid < NB) ? bsum[tid] : 0;
    int sel = 0;
    buf[0][tid] = v;
    __syncthreads();
    for (int off = 1; off < 512; off <<= 1) {
        int nsel = sel ^ 1;
        buf[nsel][tid] = buf[sel][tid] + ((tid >= off) ? buf[sel][tid - off] : 0);
        __syncthreads();
        sel = nsel;
    }
    if (tid < NB) bsum[tid] = buf[sel][tid] - v;
    if (tid == 511) offs[N] = buf[sel][511];      // grand total = E
}

__global__ void scan_add(int* __restrict__ offs, int* __restrict__ cursor,
                         const int* __restrict__ bsum, int N) {
    int i = blockIdx.x * 256 + threadIdx.x;
    if (i < N) {
        int o = offs[i] + bsum[blockIdx.x];
        offs[i] = o;
        cursor[i] = o;
    }
}

// ---------------- Kernel 6: XCD-partitioned scatter ------------------------
// Block group g = blockIdx&7 (round-robin -> XCD g, perf heuristic only)
// commits only edges with dst in range_g. Payload slice per group ~1.28 MB
// -> fits that XCD's L2 -> same-line stores merge, ~1 writeback per line.
__global__ void scatter_kernel(const float* __restrict__ ew,
                               const int* __restrict__ src_idx,
                               const int* __restrict__ dst_idx,
                               const float* __restrict__ a_src,
                               const float* __restrict__ a_dst,
                               int* __restrict__ cursor,
                               unsigned long long* __restrict__ pay,
                               int E, int N) {
    int grp   = blockIdx.x & 7;
    int slot  = blockIdx.x >> 3;
    int nslot = gridDim.x >> 3;
    int range = (N + 7) >> 3;
    unsigned lo = (unsigned)(grp * range);
    unsigned hi = lo + (unsigned)range;
    if (hi > (unsigned)N) hi = (unsigned)N;
    for (int e = slot * 256 + threadIdx.x; e < E; e += nslot * 256) {
        unsigned t = (unsigned)dst_idx[e];        // coalesced scan
        if (t < lo || t >= hi) continue;          // not ours
        unsigned s = (unsigned)src_idx[e];
        if (s >= (unsigned)N) s = 0;              // guard
        float a = tanhf(a_src[s] + a_dst[t]) * ew[e];
        int p = atomicAdd(&cursor[t], 1);         // XCD-local cursor slice
        if ((unsigned)p < (unsigned)E)            // guard (no fault)
            pay[p] = ((unsigned long long)s << 32) |
                     (unsigned long long)__float_as_uint(a);
    }
}

// ---------------- Kernel 7: gather per dst node, 8-deep batched ------------
__global__ void gather_kernel(const float* __restrict__ x,
                              const unsigned long long* __restrict__ pay,
                              const int* __restrict__ offs,
                              float* __restrict__ h,
                              int N, int E) {
    int gid  = blockIdx.x * blockDim.x + threadIdx.x;
    int t    = gid >> 6;
    int lane = threadIdx.x & 63;
    if (t >= N) return;
    int p   = offs[t];
    int end = offs[t + 1];
    if (p < 0) p = 0;
    if (end > E) end = E;
    float a0 = 0.f, a1 = 0.f, a2 = 0.f, a3 = 0.f;

    while (p + 8 <= end) {
        unsigned long long r0 = pay[p];
        unsigned long long r1 = pay[p + 1];
        unsigned long long r2 = pay[p + 2];
        unsigned long long r3 = pay[p + 3];
        unsigned long long r4 = pay[p + 4];
        unsigned long long r5 = pay[p + 5];
        unsigned long long r6 = pay[p + 6];
        unsigned long long r7 = pay[p + 7];
        p += 8;
        unsigned s0 = (unsigned)(r0 >> 32); if (s0 >= (unsigned)N) s0 = 0;
        unsigned s1 = (unsigned)(r1 >> 32); if (s1 >= (unsigned)N) s1 = 0;
        unsigned s2 = (unsigned)(r2 >> 32); if (s2 >= (unsigned)N) s2 = 0;
        unsigned s3 = (unsigned)(r3 >> 32); if (s3 >= (unsigned)N) s3 = 0;
        unsigned s4 = (unsigned)(r4 >> 32); if (s4 >= (unsigned)N) s4 = 0;
        unsigned s5 = (unsigned)(r5 >> 32); if (s5 >= (unsigned)N) s5 = 0;
        unsigned s6 = (unsigned)(r6 >> 32); if (s6 >= (unsigned)N) s6 = 0;
        unsigned s7 = (unsigned)(r7 >> 32); if (s7 >= (unsigned)N) s7 = 0;
        float x0 = x[(size_t)s0 * DIM + lane];
        float x1 = x[(size_t)s1 * DIM + lane];
        float x2 = x[(size_t)s2 * DIM + lane];
        float x3 = x[(size_t)s3 * DIM + lane];
        float x4 = x[(size_t)s4 * DIM + lane];
        float x5 = x[(size_t)s5 * DIM + lane];
        float x6 = x[(size_t)s6 * DIM + lane];
        float x7 = x[(size_t)s7 * DIM + lane];
        a0 = fmaf(__uint_as_float((unsigned)r0), x0, a0);
        a1 = fmaf(__uint_as_float((unsigned)r1), x1, a1);
        a2 = fmaf(__uint_as_float((unsigned)r2), x2, a2);
        a3 = fmaf(__uint_as_float((unsigned)r3), x3, a3);
        a0 = fmaf(__uint_as_float((unsigned)r4), x4, a0);
        a1 = fmaf(__uint_as_float((unsigned)r5), x5, a1);
        a2 = fmaf(__uint_as_float((unsigned)r6), x6, a2);
        a3 = fmaf(__uint_as_float((unsigned)r7), x7, a3);
    }
    if (p + 4 <= end) {
        unsigned long long r0 = pay[p];
        unsigned long long r1 = pay[p + 1];
        unsigned long long r2 = pay[p + 2];
        unsigned long long r3 = pay[p + 3];
        p += 4;
        unsigned s0 = (unsigned)(r0 >> 32); if (s0 >= (unsigned)N) s0 = 0;
        unsigned s1 = (unsigned)(r1 >> 32); if (s1 >= (unsigned)N) s1 = 0;
        unsigned s2 = (unsigned)(r2 >> 32); if (s2 >= (unsigned)N) s2 = 0;
        unsigned s3 = (unsigned)(r3 >> 32); if (s3 >= (unsigned)N) s3 = 0;
        float x0 = x[(size_t)s0 * DIM + lane];
        float x1 = x[(size_t)s1 * DIM + lane];
        float x2 = x[(size_t)s2 * DIM + lane];
        float x3 = x[(size_t)s3 * DIM + lane];
        a0 = fmaf(__uint_as_float((unsigned)r0), x0, a0);
        a1 = fmaf(__uint_as_float((unsigned)r1), x1, a1);
        a2 = fmaf(__uint_as_float((unsigned)r2), x2, a2);
        a3 = fmaf(__uint_as_float((unsigned)r3), x3, a3);
    }
    if (p + 2 <= end) {
        unsigned long long r0 = pay[p];
        unsigned long long r1 = pay[p + 1];
        p += 2;
        unsigned s0 = (unsigned)(r0 >> 32); if (s0 >= (unsigned)N) s0 = 0;
        unsigned s1 = (unsigned)(r1 >> 32); if (s1 >= (unsigned)N) s1 = 0;
        float x0 = x[(size_t)s0 * DIM + lane];
        float x1 = x[(size_t)s1 * DIM + lane];
        a0 = fmaf(__uint_as_float((unsigned)r0), x0, a0);
        a1 = fmaf(__uint_as_float((unsigned)r1), x1, a1);
    }
    if (p < end) {
        unsigned long long r0 = pay[p];
        unsigned s0 = (unsigned)(r0 >> 32); if (s0 >= (unsigned)N) s0 = 0;
        a0 = fmaf(__uint_as_float((unsigned)r0), x[(size_t)s0 * DIM + lane], a0);
    }
    h[(size_t)t * DIM + lane] = (a0 + a1) + (a2 + a3);
}

// ---------------- Fallback (round-1 atomic path, known-good) ---------------
__global__ void zero_out_kernel(float* __restrict__ p, int n) {
    int i = blockIdx.x * blockDim.x + threadIdx.x;
    if (i < n) p[i] = 0.f;
}

__global__ void edge_kernel_atomic(const float* __restrict__ x,
                                   const float* __restrict__ ew,
                                   const int* __restrict__ src_idx,
                                   const int* __restrict__ dst_idx,
                                   const float* __restrict__ a_src,
                                   const float* __restrict__ a_dst,
                                   float* __restrict__ h,
                                   int E) {
    int gid  = blockIdx.x * blockDim.x + threadIdx.x;
    int e    = gid >> 6;
    int lane = threadIdx.x & 63;
    if (e >= E) return;
    int s = src_idx[e];
    int t = dst_idx[e];
    float a  = tanhf(a_src[s] + a_dst[t]) * ew[e];
    float xv = x[(size_t)s * DIM + lane];
    atomicAdd(&h[(size_t)t * DIM + lane], a * xv);
}

extern "C" void kernel_launch(void* const* d_in, const int* in_sizes, int n_in,
                              void* d_out, int out_size, void* d_ws, size_t ws_size,
                              hipStream_t stream) {
    const float* x     = (const float*)d_in[0];
    const float* w_src = (const float*)d_in[1];
    const float* w_dst = (const float*)d_in[2];
    const float* ew    = (const float*)d_in[3];
    const int*   src   = (const int*)d_in[4];
    const int*   dst   = (const int*)d_in[5];
    float* h = (float*)d_out;

    int N = in_sizes[0] / DIM;
    int E = in_sizes[3];
    int NB = (N + 255) / 256;

    // ws layout (4B units):
    // [a_src N][a_dst N][cnt N][offs N+1][cursor N][bsum NB][pad->8B][pay E*8B]
    float* a_src  = (float*)d_ws;
    float* a_dst  = a_src + N;
    int*   cnt    = (int*)(a_dst + N);
    int*   offs   = cnt + N;
    int*   cursor = offs + N + 1;
    int*   bsum   = cursor + N;
    size_t head_bytes = ((size_t)(5 * N + 1 + NB)) * 4;
    size_t pay_off = (head_bytes + 15) & ~(size_t)15;
    unsigned long long* pay = (unsigned long long*)((char*)d_ws + pay_off);
    size_t need = pay_off + (size_t)E * 8;

    int score_blocks = (N + 3) / 4;
    score_kernel<<<score_blocks, 256, 0, stream>>>(x, w_src, w_dst, a_src, a_dst, N);

    if (ws_size < need || NB > 512) {
        // fallback: round-1 atomic path
        int ob = (out_size + 255) / 256;
        zero_out_kernel<<<ob, 256, 0, stream>>>(h, out_size);
        int edge_blocks = (E + 3) / 4;
        edge_kernel_atomic<<<edge_blocks, 256, 0, stream>>>(x, ew, src, dst,
                                                            a_src, a_dst, h, E);
        return;
    }

    zero_int_kernel<<<NB, 256, 0, stream>>>(cnt, N);
    int eb = (E + 255) / 256;
    hist_kernel<<<eb, 256, 0, stream>>>(dst, cnt, E, N);
    scan_part<<<NB, 256, 0, stream>>>(cnt, offs, bsum, N);
    scan_top<<<1, 512, 0, stream>>>(bsum, offs, NB, N);
    scan_add<<<NB, 256, 0, stream>>>(offs, cursor, bsum, N);
    // 2048 blocks = 8 XCD groups x 256 slots
    scatter_kernel<<<2048, 256, 0, stream>>>(ew, src, dst, a_src, a_dst,
                                             cursor, pay, E, N);
    int gather_blocks = (N + 3) / 4;
    gather_kernel<<<gather_blocks, 256, 0, stream>>>(x, pay, offs, h, N, E);
}

// Round 7
// 220.761 us; speedup vs baseline: 3.2412x; 1.2269x over previous
//
#include <hip/hip_runtime.h>
#include <math.h>

#define DIM  64
#define SPAN 256            // nodes per bucket (dst>>8)
#define NBIN 256            // binning blocks (private (block,bucket) segments)
#define KMAX 512            // max buckets (N <= 131072)
#define CAP  6144           // bucket_sort LDS staging capacity (48 KB)

// ---------------- Kernel 1: per-node scores --------------------------------
__global__ void score_kernel(const float* __restrict__ x,
                             const float* __restrict__ w_src,
                             const float* __restrict__ w_dst,
                             float* __restrict__ a_src,
                             float* __restrict__ a_dst,
                             int N) {
    int gid  = blockIdx.x * blockDim.x + threadIdx.x;
    int node = gid >> 6;
    int lane = threadIdx.x & 63;
    if (node >= N) return;
    float xv = x[(size_t)node * DIM + lane];
    float s1 = xv * w_src[lane];
    float s2 = xv * w_dst[lane];
    #pragma unroll
    for (int off = 32; off > 0; off >>= 1) {
        s1 += __shfl_down(s1, off, 64);
        s2 += __shfl_down(s2, off, 64);
    }
    if (lane == 0) {
        a_src[node] = s1;
        a_dst[node] = s2;
    }
}

// ---------------- zero h (insurance for slow path + deg-0 nodes) -----------
__global__ void zero_h_kernel(float* __restrict__ p, int n) {
    int i = blockIdx.x * blockDim.x + threadIdx.x;
    if (i < n) p[i] = 0.f;
}

// ---------------- Kernel 2: coarse histogram matrix ------------------------
// cnt[bucket * NBIN + block] = #edges of bucket seen by block. Deterministic.
__global__ void hist_coarse(const int* __restrict__ dst, int* __restrict__ cnt,
                            int E, int N, int K) {
    __shared__ int lh[KMAX];
    int tid = threadIdx.x;
    for (int j = tid; j < K; j += blockDim.x) lh[j] = 0;
    __syncthreads();
    for (int base = blockIdx.x * 256; base < E; base += NBIN * 256) {
        int e = base + tid;
        if (e < E) {
            unsigned t = (unsigned)dst[e];
            if (t >= (unsigned)N) t = 0;          // guard
            atomicAdd(&lh[t >> 8], 1);
        }
    }
    __syncthreads();
    for (int j = tid; j < K; j += blockDim.x)
        cnt[j * NBIN + blockIdx.x] = lh[j];
}

// ---------------- Kernels 3-5: exclusive scan (double-buffered HS) ---------
__global__ void scan_part(const int* __restrict__ cnt, int* __restrict__ offs,
                          int* __restrict__ bsum, int N) {
    __shared__ int buf[2][256];
    int tid = threadIdx.x;
    int i = blockIdx.x * 256 + tid;
    int v = (i < N) ? cnt[i] : 0;
    int sel = 0;
    buf[0][tid] = v;
    __syncthreads();
    for (int off = 1; off < 256; off <<= 1) {
        int nsel = sel ^ 1;
        buf[nsel][tid] = buf[sel][tid] + ((tid >= off) ? buf[sel][tid - off] : 0);
        __syncthreads();
        sel = nsel;
    }
    if (i < N) offs[i] = buf[sel][tid] - v;
    if (tid == 255) bsum[blockIdx.x] = buf[sel][255];
}

__global__ void scan_top(int* __restrict__ bsum, int* __restrict__ offs,
                         int NB, int N) {
    __shared__ int buf[2][512];
    int tid = threadIdx.x;
    int v = (tid < NB) ? bsum[tid] : 0;
    int sel = 0;
    buf[0][tid] = v;
    __syncthreads();
    for (int off = 1; off < 512; off <<= 1) {
        int nsel = sel ^ 1;
        buf[nsel][tid] = buf[sel][tid] + ((tid >= off) ? buf[sel][tid - off] : 0);
        __syncthreads();
        sel = nsel;
    }
    if (tid < NB) bsum[tid] = buf[sel][tid] - v;
    if (tid == 511) offs[N] = buf[sel][511];      // grand total = E
}

__global__ void scan_add(int* __restrict__ offs, const int* __restrict__ bsum,
                         int N) {
    int i = blockIdx.x * 256 + threadIdx.x;
    if (i < N) offs[i] += bsum[blockIdx.x];
}

// ---------------- Kernel 6: binpass — bucket-grouped payload ---------------
// Private (block,bucket) segments -> contiguous ~100B runs, no global atomics.
// pay = rec32<<32 | f32bits(a), rec32 = src<<8 | dst_local.
__global__ void binpass_kernel(const float* __restrict__ ew,
                               const int* __restrict__ src_idx,
                               const int* __restrict__ dst_idx,
                               const float* __restrict__ a_src,
                               const float* __restrict__ a_dst,
                               const int* __restrict__ moffs,
                               unsigned long long* __restrict__ pay,
                               int E, int N, int K) {
    __shared__ int lcur[KMAX];
    int tid = threadIdx.x;
    for (int j = tid; j < K; j += blockDim.x)
        lcur[j] = moffs[j * NBIN + blockIdx.x];
    __syncthreads();
    for (int base = blockIdx.x * 256; base < E; base += NBIN * 256) {
        int e = base + tid;
        if (e < E) {
            unsigned s = (unsigned)src_idx[e];
            unsigned t = (unsigned)dst_idx[e];
            if (s >= (unsigned)N) s = 0;          // guard
            if (t >= (unsigned)N) t = 0;          // guard
            float a = tanhf(a_src[s] + a_dst[t]) * ew[e];
            int bk = (int)(t >> 8);
            int pos = atomicAdd(&lcur[bk], 1);    // LDS cursor, block-local
            unsigned rec = (s << 8) | (t & 255u);
            pay[pos] = ((unsigned long long)rec << 32) |
                       (unsigned long long)__float_as_uint(a);
        }
    }
}

// ---------------- Kernel 7: per-bucket LDS counting sort -------------------
// Stage bucket fully in LDS (read-all-before-write-any -> in-place safe),
// sort by dst_local, emit per-node (start,end). Single-XCD hot-region writes.
__global__ __launch_bounds__(512) void bucket_sort_kernel(
        const float* __restrict__ x,
        unsigned long long* __restrict__ pay,
        const int* __restrict__ moffs,
        int* __restrict__ startv,
        int* __restrict__ endv,
        float* __restrict__ h,
        int N, int K) {
    __shared__ unsigned long long srec[CAP];      // 48 KB
    __shared__ int hcnt[SPAN];
    __shared__ int hoff[2][SPAN];
    __shared__ int lcur[SPAN];
    int tid = threadIdx.x;
    int b   = blockIdx.x;
    int bstart = moffs[b * NBIN];
    int bend   = moffs[(b + 1) * NBIN];           // b=K-1 -> moffs[Ntot]=E
    int cnt = bend - bstart;

    if (cnt <= CAP) {
        // ---- fast path: staged in-place counting sort ----
        if (tid < SPAN) hcnt[tid] = 0;
        __syncthreads();
        for (int i = tid; i < cnt; i += 512) {
            unsigned long long r = pay[bstart + i];
            srec[i] = r;
            atomicAdd(&hcnt[(int)((r >> 32) & 255u)], 1);
        }
        __syncthreads();
        // inclusive scan of hcnt[256]
        int sel = 0;
        if (tid < SPAN) hoff[0][tid] = hcnt[tid];
        __syncthreads();
        for (int off = 1; off < SPAN; off <<= 1) {
            int nsel = sel ^ 1;
            if (tid < SPAN)
                hoff[nsel][tid] = hoff[sel][tid] +
                                  ((tid >= off) ? hoff[sel][tid - off] : 0);
            __syncthreads();
            sel = nsel;
        }
        if (tid < SPAN) {
            int incl = hoff[sel][tid];
            int excl = incl - hcnt[tid];
            lcur[tid] = bstart + excl;
            int node = b * SPAN + tid;
            if (node < N) {
                startv[node] = bstart + excl;
                endv[node]   = bstart + incl;
            }
        }
        __syncthreads();
        // in-place permute (all reads already staged)
        for (int i = tid; i < cnt; i += 512) {
            unsigned long long r = srec[i];
            int d = (int)((r >> 32) & 255u);
            int pos = atomicAdd(&lcur[d], 1);
            pay[pos] = r;
        }
    } else {
        // ---- slow path (never taken for this input, correctness only) ----
        if (tid < SPAN) {
            int node = b * SPAN + tid;
            if (node < N) { startv[node] = bstart; endv[node] = bstart; }
        }
        __syncthreads();
        for (int i = tid; i < cnt; i += 512) {
            unsigned long long r = pay[bstart + i];
            unsigned s = (unsigned)(r >> 40);
            if (s >= (unsigned)N) s = 0;
            int node = b * SPAN + (int)((r >> 32) & 255u);
            float a = __uint_as_float((unsigned)r);
            if (node < N)
                for (int k = 0; k < DIM; ++k)
                    atomicAdd(&h[(size_t)node * DIM + k],
                              a * x[(size_t)s * DIM + k]);
        }
    }
}

// ---------------- Kernel 8: gather per dst node, 8-deep batched ------------
__global__ void gather_kernel(const float* __restrict__ x,
                              const unsigned long long* __restrict__ pay,
                              const int* __restrict__ startv,
                              const int* __restrict__ endv,
                              float* __restrict__ h,
                              int N, int E) {
    int gid  = blockIdx.x * blockDim.x + threadIdx.x;
    int t    = gid >> 6;
    int lane = threadIdx.x & 63;
    if (t >= N) return;
    int p   = startv[t];
    int end = endv[t];
    if (p < 0) p = 0;
    if (end > E) end = E;
    if (p >= end) return;                  // deg-0 / slow-path: h stays as-is
    float a0 = 0.f, a1 = 0.f, a2 = 0.f, a3 = 0.f;

    while (p + 8 <= end) {
        unsigned long long r0 = pay[p];
        unsigned long long r1 = pay[p + 1];
        unsigned long long r2 = pay[p + 2];
        unsigned long long r3 = pay[p + 3];
        unsigned long long r4 = pay[p + 4];
        unsigned long long r5 = pay[p + 5];
        unsigned long long r6 = pay[p + 6];
        unsigned long long r7 = pay[p + 7];
        p += 8;
        unsigned s0 = (unsigned)(r0 >> 40); if (s0 >= (unsigned)N) s0 = 0;
        unsigned s1 = (unsigned)(r1 >> 40); if (s1 >= (unsigned)N) s1 = 0;
        unsigned s2 = (unsigned)(r2 >> 40); if (s2 >= (unsigned)N) s2 = 0;
        unsigned s3 = (unsigned)(r3 >> 40); if (s3 >= (unsigned)N) s3 = 0;
        unsigned s4 = (unsigned)(r4 >> 40); if (s4 >= (unsigned)N) s4 = 0;
        unsigned s5 = (unsigned)(r5 >> 40); if (s5 >= (unsigned)N) s5 = 0;
        unsigned s6 = (unsigned)(r6 >> 40); if (s6 >= (unsigned)N) s6 = 0;
        unsigned s7 = (unsigned)(r7 >> 40); if (s7 >= (unsigned)N) s7 = 0;
        float x0 = x[(size_t)s0 * DIM + lane];
        float x1 = x[(size_t)s1 * DIM + lane];
        float x2 = x[(size_t)s2 * DIM + lane];
        float x3 = x[(size_t)s3 * DIM + lane];
        float x4 = x[(size_t)s4 * DIM + lane];
        float x5 = x[(size_t)s5 * DIM + lane];
        float x6 = x[(size_t)s6 * DIM + lane];
        float x7 = x[(size_t)s7 * DIM + lane];
        a0 = fmaf(__uint_as_float((unsigned)r0), x0, a0);
        a1 = fmaf(__uint_as_float((unsigned)r1), x1, a1);
        a2 = fmaf(__uint_as_float((unsigned)r2), x2, a2);
        a3 = fmaf(__uint_as_float((unsigned)r3), x3, a3);
        a0 = fmaf(__uint_as_float((unsigned)r4), x4, a0);
        a1 = fmaf(__uint_as_float((unsigned)r5), x5, a1);
        a2 = fmaf(__uint_as_float((unsigned)r6), x6, a2);
        a3 = fmaf(__uint_as_float((unsigned)r7), x7, a3);
    }
    if (p + 4 <= end) {
        unsigned long long r0 = pay[p];
        unsigned long long r1 = pay[p + 1];
        unsigned long long r2 = pay[p + 2];
        unsigned long long r3 = pay[p + 3];
        p += 4;
        unsigned s0 = (unsigned)(r0 >> 40); if (s0 >= (unsigned)N) s0 = 0;
        unsigned s1 = (unsigned)(r1 >> 40); if (s1 >= (unsigned)N) s1 = 0;
        unsigned s2 = (unsigned)(r2 >> 40); if (s2 >= (unsigned)N) s2 = 0;
        unsigned s3 = (unsigned)(r3 >> 40); if (s3 >= (unsigned)N) s3 = 0;
        float x0 = x[(size_t)s0 * DIM + lane];
        float x1 = x[(size_t)s1 * DIM + lane];
        float x2 = x[(size_t)s2 * DIM + lane];
        float x3 = x[(size_t)s3 * DIM + lane];
        a0 = fmaf(__uint_as_float((unsigned)r0), x0, a0);
        a1 = fmaf(__uint_as_float((unsigned)r1), x1, a1);
        a2 = fmaf(__uint_as_float((unsigned)r2), x2, a2);
        a3 = fmaf(__uint_as_float((unsigned)r3), x3, a3);
    }
    if (p + 2 <= end) {
        unsigned long long r0 = pay[p];
        unsigned long long r1 = pay[p + 1];
        p += 2;
        unsigned s0 = (unsigned)(r0 >> 40); if (s0 >= (unsigned)N) s0 = 0;
        unsigned s1 = (unsigned)(r1 >> 40); if (s1 >= (unsigned)N) s1 = 0;
        float x0 = x[(size_t)s0 * DIM + lane];
        float x1 = x[(size_t)s1 * DIM + lane];
        a0 = fmaf(__uint_as_float((unsigned)r0), x0, a0);
        a1 = fmaf(__uint_as_float((unsigned)r1), x1, a1);
    }
    if (p < end) {
        unsigned long long r0 = pay[p];
        unsigned s0 = (unsigned)(r0 >> 40); if (s0 >= (unsigned)N) s0 = 0;
        a0 = fmaf(__uint_as_float((unsigned)r0), x[(size_t)s0 * DIM + lane], a0);
    }
    h[(size_t)t * DIM + lane] = (a0 + a1) + (a2 + a3);
}

// ---------------- Fallback (round-1 atomic path, known-good) ---------------
__global__ void edge_kernel_atomic(const float* __restrict__ x,
                                   const float* __restrict__ ew,
                                   const int* __restrict__ src_idx,
                                   const int* __restrict__ dst_idx,
                                   const float* __restrict__ a_src,
                                   const float* __restrict__ a_dst,
                                   float* __restrict__ h,
                                   int E) {
    int gid  = blockIdx.x * blockDim.x + threadIdx.x;
    int e    = gid >> 6;
    int lane = threadIdx.x & 63;
    if (e >= E) return;
    int s = src_idx[e];
    int t = dst_idx[e];
    float a  = tanhf(a_src[s] + a_dst[t]) * ew[e];
    float xv = x[(size_t)s * DIM + lane];
    atomicAdd(&h[(size_t)t * DIM + lane], a * xv);
}

extern "C" void kernel_launch(void* const* d_in, const int* in_sizes, int n_in,
                              void* d_out, int out_size, void* d_ws, size_t ws_size,
                              hipStream_t stream) {
    const float* x     = (const float*)d_in[0];
    const float* w_src = (const float*)d_in[1];
    const float* w_dst = (const float*)d_in[2];
    const float* ew    = (const float*)d_in[3];
    const int*   src   = (const int*)d_in[4];
    const int*   dst   = (const int*)d_in[5];
    float* h = (float*)d_out;

    int N = in_sizes[0] / DIM;
    int E = in_sizes[3];

    int K    = (N + SPAN - 1) / SPAN;     // buckets
    int Ntot = K * NBIN;                  // count-matrix entries
    int NBs  = (Ntot + 255) / 256;        // scan blocks

    // ws layout (4B units):
    // [a_src N][a_dst N][startv N][endv N][moffs Ntot+1][bsum NBs][pad][pay E*8B]
    float* a_src  = (float*)d_ws;
    float* a_dst  = a_src + N;
    int*   startv = (int*)(a_dst + N);
    int*   endv   = startv + N;
    int*   moffs  = endv + N;
    int*   bsum   = moffs + Ntot + 1;
    size_t head_bytes = ((size_t)(4 * N) + (size_t)Ntot + 1 + (size_t)NBs) * 4;
    size_t pay_off = (head_bytes + 15) & ~(size_t)15;
    unsigned long long* pay = (unsigned long long*)((char*)d_ws + pay_off);
    size_t need = pay_off + (size_t)E * 8;

    int score_blocks = (N + 3) / 4;
    score_kernel<<<score_blocks, 256, 0, stream>>>(x, w_src, w_dst, a_src, a_dst, N);

    if (ws_size < need || K > KMAX || NBs > 512) {
        // fallback: round-1 atomic path
        int ob = (out_size + 255) / 256;
        zero_h_kernel<<<ob, 256, 0, stream>>>(h, out_size);
        int edge_blocks = (E + 3) / 4;
        edge_kernel_atomic<<<edge_blocks, 256, 0, stream>>>(x, ew, src, dst,
                                                            a_src, a_dst, h, E);
        return;
    }

    int ob = (out_size + 255) / 256;
    zero_h_kernel<<<ob, 256, 0, stream>>>(h, out_size);   // deg-0 + slow-path insurance
    hist_coarse<<<NBIN, 256, 0, stream>>>(dst, (int*)moffs, E, N, K);
    // scan cnt (stored in moffs? no: hist wrote into moffs as cnt) — scan in place:
    scan_part<<<NBs, 256, 0, stream>>>(moffs, moffs, bsum, Ntot);
    scan_top<<<1, 512, 0, stream>>>(bsum, moffs, NBs, Ntot);
    scan_add<<<NBs, 256, 0, stream>>>(moffs, bsum, Ntot);
    binpass_kernel<<<NBIN, 256, 0, stream>>>(ew, src, dst, a_src, a_dst,
                                             moffs, pay, E, N, K);
    bucket_sort_kernel<<<K, 512, 0, stream>>>(x, pay, moffs, startv, endv, h, N, K);
    int gather_blocks = (N + 3) / 4;
    gather_kernel<<<gather_blocks, 256, 0, stream>>>(x, pay, startv, endv, h, N, E);
}

// Round 8
// 196.802 us; speedup vs baseline: 3.6358x; 1.1217x over previous
//
#include <hip/hip_runtime.h>
#include <hip/hip_fp16.h>
#include <math.h>

#define DIM  64
#define SPAN 256            // nodes per bucket (dst>>8)
#define NBIN 256            // binning blocks (private (block,bucket) segments)
#define KMAX 512            // max buckets (N <= 131072)
#define CAP  6144           // bucket_sort LDS staging capacity (48 KB)

// ---------------- Kernel 1: per-node scores --------------------------------
__global__ void score_kernel(const float* __restrict__ x,
                             const float* __restrict__ w_src,
                             const float* __restrict__ w_dst,
                             float* __restrict__ a_src,
                             float* __restrict__ a_dst,
                             int N) {
    int gid  = blockIdx.x * blockDim.x + threadIdx.x;
    int node = gid >> 6;
    int lane = threadIdx.x & 63;
    if (node >= N) return;
    float xv = x[(size_t)node * DIM + lane];
    float s1 = xv * w_src[lane];
    float s2 = xv * w_dst[lane];
    #pragma unroll
    for (int off = 32; off > 0; off >>= 1) {
        s1 += __shfl_down(s1, off, 64);
        s2 += __shfl_down(s2, off, 64);
    }
    if (lane == 0) {
        a_src[node] = s1;
        a_dst[node] = s2;
    }
}

// ---------------- Kernel 1b: x -> fp16 copy (halves gather fetch) ----------
__global__ void xhalf_kernel(const float* __restrict__ x,
                             __half* __restrict__ xh, int total2) {
    int i = blockIdx.x * blockDim.x + threadIdx.x;   // one __half2 per thread
    if (i >= total2) return;
    float2 v = ((const float2*)x)[i];
    ((__half2*)xh)[i] = __floats2half2_rn(v.x, v.y);
}

// ---------------- Kernel 2: coarse histogram matrix ------------------------
// cnt[bucket * NBIN + block] = #edges of bucket seen by block. Deterministic.
__global__ __launch_bounds__(1024) void hist_coarse(
        const int* __restrict__ dst, int* __restrict__ cnt,
        int E, int N, int K) {
    __shared__ int lh[KMAX];
    int tid = threadIdx.x;
    for (int j = tid; j < K; j += blockDim.x) lh[j] = 0;
    __syncthreads();
    for (int base = blockIdx.x * 1024; base < E; base += NBIN * 1024) {
        int e = base + tid;
        if (e < E) {
            unsigned t = (unsigned)dst[e];
            if (t >= (unsigned)N) t = 0;          // guard
            atomicAdd(&lh[t >> 8], 1);
        }
    }
    __syncthreads();
    for (int j = tid; j < K; j += blockDim.x)
        cnt[j * NBIN + blockIdx.x] = lh[j];
}

// ---------------- Kernels 3-4: exclusive scan (double-buffered HS) ---------
// scan_part is in-place safe (stages into LDS before any write).
__global__ void scan_part(const int* __restrict__ cnt, int* __restrict__ offs,
                          int* __restrict__ bsum, int N) {
    __shared__ int buf[2][256];
    int tid = threadIdx.x;
    int i = blockIdx.x * 256 + tid;
    int v = (i < N) ? cnt[i] : 0;
    int sel = 0;
    buf[0][tid] = v;
    __syncthreads();
    for (int off = 1; off < 256; off <<= 1) {
        int nsel = sel ^ 1;
        buf[nsel][tid] = buf[sel][tid] + ((tid >= off) ? buf[sel][tid - off] : 0);
        __syncthreads();
        sel = nsel;
    }
    if (i < N) offs[i] = buf[sel][tid] - v;
    if (tid == 255) bsum[blockIdx.x] = buf[sel][255];
}

__global__ void scan_top(int* __restrict__ bsum, int* __restrict__ offs,
                         int NB, int N) {
    __shared__ int buf[2][512];
    int tid = threadIdx.x;
    int v = (tid < NB) ? bsum[tid] : 0;
    int sel = 0;
    buf[0][tid] = v;
    __syncthreads();
    for (int off = 1; off < 512; off <<= 1) {
        int nsel = sel ^ 1;
        buf[nsel][tid] = buf[sel][tid] + ((tid >= off) ? buf[sel][tid - off] : 0);
        __syncthreads();
        sel = nsel;
    }
    if (tid < NB) bsum[tid] = buf[sel][tid] - v;
    if (tid == 511) offs[N] = buf[sel][511];      // grand total = E (unused)
}

// ---------------- Kernel 5: binpass — bucket-grouped payload ---------------
// Base-add fused: absolute offset = moffs[i] + bsum[i>>8].
// pay = rec32<<32 | f32bits(a), rec32 = src<<8 | dst_local.
__global__ __launch_bounds__(1024) void binpass_kernel(
        const float* __restrict__ ew,
        const int* __restrict__ src_idx,
        const int* __restrict__ dst_idx,
        const float* __restrict__ a_src,
        const float* __restrict__ a_dst,
        const int* __restrict__ moffs,
        const int* __restrict__ bsum,
        unsigned long long* __restrict__ pay,
        int E, int N, int K) {
    __shared__ int lcur[KMAX];
    int tid = threadIdx.x;
    for (int j = tid; j < K; j += blockDim.x) {
        int i = j * NBIN + blockIdx.x;
        lcur[j] = moffs[i] + bsum[i >> 8];
    }
    __syncthreads();
    for (int base = blockIdx.x * 1024; base < E; base += NBIN * 1024) {
        int e = base + tid;
        if (e < E) {
            unsigned s = (unsigned)src_idx[e];
            unsigned t = (unsigned)dst_idx[e];
            if (s >= (unsigned)N) s = 0;          // guard
            if (t >= (unsigned)N) t = 0;          // guard
            float a = tanhf(a_src[s] + a_dst[t]) * ew[e];
            int bk = (int)(t >> 8);
            int pos = atomicAdd(&lcur[bk], 1);    // LDS cursor, block-local
            unsigned rec = (s << 8) | (t & 255u);
            pay[pos] = ((unsigned long long)rec << 32) |
                       (unsigned long long)__float_as_uint(a);
        }
    }
}

// ---------------- Kernel 6: per-bucket LDS counting sort -------------------
// Stage bucket fully in LDS, sort by dst_local, emit per-node (start,end).
// Slow path (cnt>CAP, never for this input): self-zeroes h, accumulates
// atomically, marks startv=-1 so gather skips those nodes.
__global__ __launch_bounds__(1024) void bucket_sort_kernel(
        const float* __restrict__ x,
        unsigned long long* __restrict__ pay,
        const int* __restrict__ moffs,
        const int* __restrict__ bsum,
        int* __restrict__ startv,
        int* __restrict__ endv,
        float* __restrict__ h,
        int N, int K, int E) {
    __shared__ unsigned long long srec[CAP];      // 48 KB
    __shared__ int hcnt[SPAN];
    __shared__ int hoff[2][SPAN];
    __shared__ int lcur[SPAN];
    int tid = threadIdx.x;
    int b   = blockIdx.x;
    int i0 = b * NBIN;
    int bstart = moffs[i0] + bsum[i0 >> 8];
    int bend;
    if (b == K - 1) bend = E;
    else { int i1 = (b + 1) * NBIN; bend = moffs[i1] + bsum[i1 >> 8]; }
    int cnt = bend - bstart;

    if (cnt <= CAP) {
        // ---- fast path: staged in-place counting sort ----
        if (tid < SPAN) hcnt[tid] = 0;
        __syncthreads();
        for (int i = tid; i < cnt; i += 1024) {
            unsigned long long r = pay[bstart + i];
            srec[i] = r;
            atomicAdd(&hcnt[(int)((r >> 32) & 255u)], 1);
        }
        __syncthreads();
        int sel = 0;
        if (tid < SPAN) hoff[0][tid] = hcnt[tid];
        __syncthreads();
        for (int off = 1; off < SPAN; off <<= 1) {
            int nsel = sel ^ 1;
            if (tid < SPAN)
                hoff[nsel][tid] = hoff[sel][tid] +
                                  ((tid >= off) ? hoff[sel][tid - off] : 0);
            __syncthreads();
            sel = nsel;
        }
        if (tid < SPAN) {
            int incl = hoff[sel][tid];
            int excl = incl - hcnt[tid];
            lcur[tid] = bstart + excl;
            int node = b * SPAN + tid;
            if (node < N) {
                startv[node] = bstart + excl;
                endv[node]   = bstart + incl;
            }
        }
        __syncthreads();
        for (int i = tid; i < cnt; i += 1024) {
            unsigned long long r = srec[i];
            int d = (int)((r >> 32) & 255u);
            int pos = atomicAdd(&lcur[d], 1);
            pay[pos] = r;
        }
    } else {
        // ---- slow path (correctness only) ----
        if (tid < SPAN) {
            int node = b * SPAN + tid;
            if (node < N) startv[node] = -1;      // gather skips
        }
        // zero own nodes' h rows (this block is the sole writer for them)
        for (int j = tid; j < SPAN * DIM; j += 1024) {
            int node = b * SPAN + (j >> 6);
            if (node < N) h[(size_t)node * DIM + (j & 63)] = 0.f;
        }
        __syncthreads();
        for (int i = tid; i < cnt; i += 1024) {
            unsigned long long r = pay[bstart + i];
            unsigned s = (unsigned)(r >> 40);
            if (s >= (unsigned)N) s = 0;
            int node = b * SPAN + (int)((r >> 32) & 255u);
            float a = __uint_as_float((unsigned)r);
            if (node < N)
                for (int k = 0; k < DIM; ++k)
                    atomicAdd(&h[(size_t)node * DIM + k],
                              a * x[(size_t)s * DIM + k]);
        }
    }
}

// ---------------- Kernel 7: gather (fp16 x), 8-deep batched ----------------
__global__ void gather_f16_kernel(const __half* __restrict__ xh,
                                  const unsigned long long* __restrict__ pay,
                                  const int* __restrict__ startv,
                                  const int* __restrict__ endv,
                                  float* __restrict__ h,
                                  int N, int E) {
    int gid  = blockIdx.x * blockDim.x + threadIdx.x;
    int t    = gid >> 6;
    int lane = threadIdx.x & 63;
    if (t >= N) return;
    int p = startv[t];
    if (p < 0) return;                    // slow-path bucket: h owned by atomics
    int end = endv[t];
    if (end > E) end = E;
    float a0 = 0.f, a1 = 0.f, a2 = 0.f, a3 = 0.f;

    while (p + 8 <= end) {
        unsigned long long r0 = pay[p];
        unsigned long long r1 = pay[p + 1];
        unsigned long long r2 = pay[p + 2];
        unsigned long long r3 = pay[p + 3];
        unsigned long long r4 = pay[p + 4];
        unsigned long long r5 = pay[p + 5];
        unsigned long long r6 = pay[p + 6];
        unsigned long long r7 = pay[p + 7];
        p += 8;
        unsigned s0 = (unsigned)(r0 >> 40); if (s0 >= (unsigned)N) s0 = 0;
        unsigned s1 = (unsigned)(r1 >> 40); if (s1 >= (unsigned)N) s1 = 0;
        unsigned s2 = (unsigned)(r2 >> 40); if (s2 >= (unsigned)N) s2 = 0;
        unsigned s3 = (unsigned)(r3 >> 40); if (s3 >= (unsigned)N) s3 = 0;
        unsigned s4 = (unsigned)(r4 >> 40); if (s4 >= (unsigned)N) s4 = 0;
        unsigned s5 = (unsigned)(r5 >> 40); if (s5 >= (unsigned)N) s5 = 0;
        unsigned s6 = (unsigned)(r6 >> 40); if (s6 >= (unsigned)N) s6 = 0;
        unsigned s7 = (unsigned)(r7 >> 40); if (s7 >= (unsigned)N) s7 = 0;
        float x0 = __half2float(xh[(size_t)s0 * DIM + lane]);
        float x1 = __half2float(xh[(size_t)s1 * DIM + lane]);
        float x2 = __half2float(xh[(size_t)s2 * DIM + lane]);
        float x3 = __half2float(xh[(size_t)s3 * DIM + lane]);
        float x4 = __half2float(xh[(size_t)s4 * DIM + lane]);
        float x5 = __half2float(xh[(size_t)s5 * DIM + lane]);
        float x6 = __half2float(xh[(size_t)s6 * DIM + lane]);
        float x7 = __half2float(xh[(size_t)s7 * DIM + lane]);
        a0 = fmaf(__uint_as_float((unsigned)r0), x0, a0);
        a1 = fmaf(__uint_as_float((unsigned)r1), x1, a1);
        a2 = fmaf(__uint_as_float((unsigned)r2), x2, a2);
        a3 = fmaf(__uint_as_float((unsigned)r3), x3, a3);
        a0 = fmaf(__uint_as_float((unsigned)r4), x4, a0);
        a1 = fmaf(__uint_as_float((unsigned)r5), x5, a1);
        a2 = fmaf(__uint_as_float((unsigned)r6), x6, a2);
        a3 = fmaf(__uint_as_float((unsigned)r7), x7, a3);
    }
    if (p + 4 <= end) {
        unsigned long long r0 = pay[p];
        unsigned long long r1 = pay[p + 1];
        unsigned long long r2 = pay[p + 2];
        unsigned long long r3 = pay[p + 3];
        p += 4;
        unsigned s0 = (unsigned)(r0 >> 40); if (s0 >= (unsigned)N) s0 = 0;
        unsigned s1 = (unsigned)(r1 >> 40); if (s1 >= (unsigned)N) s1 = 0;
        unsigned s2 = (unsigned)(r2 >> 40); if (s2 >= (unsigned)N) s2 = 0;
        unsigned s3 = (unsigned)(r3 >> 40); if (s3 >= (unsigned)N) s3 = 0;
        float x0 = __half2float(xh[(size_t)s0 * DIM + lane]);
        float x1 = __half2float(xh[(size_t)s1 * DIM + lane]);
        float x2 = __half2float(xh[(size_t)s2 * DIM + lane]);
        float x3 = __half2float(xh[(size_t)s3 * DIM + lane]);
        a0 = fmaf(__uint_as_float((unsigned)r0), x0, a0);
        a1 = fmaf(__uint_as_float((unsigned)r1), x1, a1);
        a2 = fmaf(__uint_as_float((unsigned)r2), x2, a2);
        a3 = fmaf(__uint_as_float((unsigned)r3), x3, a3);
    }
    if (p + 2 <= end) {
        unsigned long long r0 = pay[p];
        unsigned long long r1 = pay[p + 1];
        p += 2;
        unsigned s0 = (unsigned)(r0 >> 40); if (s0 >= (unsigned)N) s0 = 0;
        unsigned s1 = (unsigned)(r1 >> 40); if (s1 >= (unsigned)N) s1 = 0;
        a0 = fmaf(__uint_as_float((unsigned)r0),
                  __half2float(xh[(size_t)s0 * DIM + lane]), a0);
        a1 = fmaf(__uint_as_float((unsigned)r1),
                  __half2float(xh[(size_t)s1 * DIM + lane]), a1);
    }
    if (p < end) {
        unsigned long long r0 = pay[p];
        unsigned s0 = (unsigned)(r0 >> 40); if (s0 >= (unsigned)N) s0 = 0;
        a0 = fmaf(__uint_as_float((unsigned)r0),
                  __half2float(xh[(size_t)s0 * DIM + lane]), a0);
    }
    h[(size_t)t * DIM + lane] = (a0 + a1) + (a2 + a3);  // deg-0 writes 0
}

// ---------------- Kernel 7 alt: gather (fp32 x), ws-constrained tier -------
__global__ void gather_f32_kernel(const float* __restrict__ x,
                                  const unsigned long long* __restrict__ pay,
                                  const int* __restrict__ startv,
                                  const int* __restrict__ endv,
                                  float* __restrict__ h,
                                  int N, int E) {
    int gid  = blockIdx.x * blockDim.x + threadIdx.x;
    int t    = gid >> 6;
    int lane = threadIdx.x & 63;
    if (t >= N) return;
    int p = startv[t];
    if (p < 0) return;
    int end = endv[t];
    if (end > E) end = E;
    float a0 = 0.f, a1 = 0.f, a2 = 0.f, a3 = 0.f;
    while (p + 4 <= end) {
        unsigned long long r0 = pay[p];
        unsigned long long r1 = pay[p + 1];
        unsigned long long r2 = pay[p + 2];
        unsigned long long r3 = pay[p + 3];
        p += 4;
        unsigned s0 = (unsigned)(r0 >> 40); if (s0 >= (unsigned)N) s0 = 0;
        unsigned s1 = (unsigned)(r1 >> 40); if (s1 >= (unsigned)N) s1 = 0;
        unsigned s2 = (unsigned)(r2 >> 40); if (s2 >= (unsigned)N) s2 = 0;
        unsigned s3 = (unsigned)(r3 >> 40); if (s3 >= (unsigned)N) s3 = 0;
        a0 = fmaf(__uint_as_float((unsigned)r0), x[(size_t)s0 * DIM + lane], a0);
        a1 = fmaf(__uint_as_float((unsigned)r1), x[(size_t)s1 * DIM + lane], a1);
        a2 = fmaf(__uint_as_float((unsigned)r2), x[(size_t)s2 * DIM + lane], a2);
        a3 = fmaf(__uint_as_float((unsigned)r3), x[(size_t)s3 * DIM + lane], a3);
    }
    for (; p < end; ++p) {
        unsigned long long r0 = pay[p];
        unsigned s0 = (unsigned)(r0 >> 40); if (s0 >= (unsigned)N) s0 = 0;
        a0 = fmaf(__uint_as_float((unsigned)r0), x[(size_t)s0 * DIM + lane], a0);
    }
    h[(size_t)t * DIM + lane] = (a0 + a1) + (a2 + a3);
}

// ---------------- Fallback (round-1 atomic path, known-good) ---------------
__global__ void zero_h_kernel(float* __restrict__ p, int n) {
    int i = blockIdx.x * blockDim.x + threadIdx.x;
    if (i < n) p[i] = 0.f;
}

__global__ void edge_kernel_atomic(const float* __restrict__ x,
                                   const float* __restrict__ ew,
                                   const int* __restrict__ src_idx,
                                   const int* __restrict__ dst_idx,
                                   const float* __restrict__ a_src,
                                   const float* __restrict__ a_dst,
                                   float* __restrict__ h,
                                   int E) {
    int gid  = blockIdx.x * blockDim.x + threadIdx.x;
    int e    = gid >> 6;
    int lane = threadIdx.x & 63;
    if (e >= E) return;
    int s = src_idx[e];
    int t = dst_idx[e];
    float a  = tanhf(a_src[s] + a_dst[t]) * ew[e];
    float xv = x[(size_t)s * DIM + lane];
    atomicAdd(&h[(size_t)t * DIM + lane], a * xv);
}

extern "C" void kernel_launch(void* const* d_in, const int* in_sizes, int n_in,
                              void* d_out, int out_size, void* d_ws, size_t ws_size,
                              hipStream_t stream) {
    const float* x     = (const float*)d_in[0];
    const float* w_src = (const float*)d_in[1];
    const float* w_dst = (const float*)d_in[2];
    const float* ew    = (const float*)d_in[3];
    const int*   src   = (const int*)d_in[4];
    const int*   dst   = (const int*)d_in[5];
    float* h = (float*)d_out;

    int N = in_sizes[0] / DIM;
    int E = in_sizes[3];

    int K    = (N + SPAN - 1) / SPAN;     // buckets
    int Ntot = K * NBIN;                  // count-matrix entries
    int NBs  = (Ntot + 255) / 256;        // scan blocks

    // ws layout (4B units):
    // [a_src N][a_dst N][startv N][endv N][moffs Ntot+1][bsum NBs][pad]
    // [pay E*8B][xh N*DIM*2B]
    float* a_src  = (float*)d_ws;
    float* a_dst  = a_src + N;
    int*   startv = (int*)(a_dst + N);
    int*   endv   = startv + N;
    int*   moffs  = endv + N;
    int*   bsum   = moffs + Ntot + 1;
    size_t head_bytes = ((size_t)(4 * N) + (size_t)Ntot + 1 + (size_t)NBs) * 4;
    size_t pay_off = (head_bytes + 15) & ~(size_t)15;
    unsigned long long* pay = (unsigned long long*)((char*)d_ws + pay_off);
    size_t xh_off = pay_off + (size_t)E * 8;
    __half* xh = (__half*)((char*)d_ws + xh_off);
    size_t need_sort = pay_off + (size_t)E * 8;
    size_t need_f16  = xh_off + (size_t)N * DIM * 2;

    int score_blocks = (N + 3) / 4;
    score_kernel<<<score_blocks, 256, 0, stream>>>(x, w_src, w_dst, a_src, a_dst, N);

    if (ws_size < need_sort || K > KMAX || NBs > 512) {
        // fallback: round-1 atomic path
        int ob = (out_size + 255) / 256;
        zero_h_kernel<<<ob, 256, 0, stream>>>(h, out_size);
        int edge_blocks = (E + 3) / 4;
        edge_kernel_atomic<<<edge_blocks, 256, 0, stream>>>(x, ew, src, dst,
                                                            a_src, a_dst, h, E);
        return;
    }

    bool use_f16 = (ws_size >= need_f16);
    if (use_f16) {
        int total2 = N * DIM / 2;
        xhalf_kernel<<<(total2 + 255) / 256, 256, 0, stream>>>(x, xh, total2);
    }

    hist_coarse<<<NBIN, 1024, 0, stream>>>(dst, moffs, E, N, K);
    scan_part<<<NBs, 256, 0, stream>>>(moffs, moffs, bsum, Ntot);
    scan_top<<<1, 512, 0, stream>>>(bsum, moffs, NBs, Ntot);
    binpass_kernel<<<NBIN, 1024, 0, stream>>>(ew, src, dst, a_src, a_dst,
                                              moffs, bsum, pay, E, N, K);
    bucket_sort_kernel<<<K, 1024, 0, stream>>>(x, pay, moffs, bsum,
                                               startv, endv, h, N, K, E);
    int gather_blocks = (N + 3) / 4;
    if (use_f16)
        gather_f16_kernel<<<gather_blocks, 256, 0, stream>>>(xh, pay, startv,
                                                             endv, h, N, E);
    else
        gather_f32_kernel<<<gather_blocks, 256, 0, stream>>>(x, pay, startv,
                                                             endv, h, N, E);
}

// Round 9
// 185.937 us; speedup vs baseline: 3.8483x; 1.0584x over previous
//
#include <hip/hip_runtime.h>
#include <hip/hip_fp16.h>
#include <math.h>

#define DIM  64
#define SPAN 256            // nodes per bucket (dst>>8)
#define NBIN 256            // binning blocks (private (block,bucket) segments)
#define KMAX 512            // max buckets (N <= 131072)
#define CAP  6144           // LDS staging capacity per bucket (48 KB)

// ---------------- Kernel 1: per-node scores + fp16 x copy ------------------
// One wave per node. Emits xh while x row is already in registers.
__global__ void score_kernel(const float* __restrict__ x,
                             const float* __restrict__ w_src,
                             const float* __restrict__ w_dst,
                             float* __restrict__ a_src,
                             float* __restrict__ a_dst,
                             __half* __restrict__ xh,
                             int N) {
    int gid  = blockIdx.x * blockDim.x + threadIdx.x;
    int node = gid >> 6;
    int lane = threadIdx.x & 63;
    if (node >= N) return;
    float xv = x[(size_t)node * DIM + lane];
    xh[(size_t)node * DIM + lane] = __float2half_rn(xv);
    float s1 = xv * w_src[lane];
    float s2 = xv * w_dst[lane];
    #pragma unroll
    for (int off = 32; off > 0; off >>= 1) {
        s1 += __shfl_down(s1, off, 64);
        s2 += __shfl_down(s2, off, 64);
    }
    if (lane == 0) {
        a_src[node] = s1;
        a_dst[node] = s2;
    }
}

// ---------------- Kernel 2: coarse histogram matrix ------------------------
// cnt[bucket * NBIN + block] = #edges of bucket seen by block. Deterministic.
__global__ __launch_bounds__(1024) void hist_coarse(
        const int* __restrict__ dst, int* __restrict__ cnt,
        int E, int N, int K) {
    __shared__ int lh[KMAX];
    int tid = threadIdx.x;
    for (int j = tid; j < K; j += blockDim.x) lh[j] = 0;
    __syncthreads();
    for (int base = blockIdx.x * 1024; base < E; base += NBIN * 1024) {
        int e = base + tid;
        if (e < E) {
            unsigned t = (unsigned)dst[e];
            if (t >= (unsigned)N) t = 0;          // guard
            atomicAdd(&lh[t >> 8], 1);
        }
    }
    __syncthreads();
    for (int j = tid; j < K; j += blockDim.x)
        cnt[j * NBIN + blockIdx.x] = lh[j];
}

// ---------------- Kernels 3-4: exclusive scan (double-buffered HS) ---------
// scan_part is in-place safe (stages into LDS before any write).
__global__ void scan_part(const int* __restrict__ cnt, int* __restrict__ offs,
                          int* __restrict__ bsum, int N) {
    __shared__ int buf[2][256];
    int tid = threadIdx.x;
    int i = blockIdx.x * 256 + tid;
    int v = (i < N) ? cnt[i] : 0;
    int sel = 0;
    buf[0][tid] = v;
    __syncthreads();
    for (int off = 1; off < 256; off <<= 1) {
        int nsel = sel ^ 1;
        buf[nsel][tid] = buf[sel][tid] + ((tid >= off) ? buf[sel][tid - off] : 0);
        __syncthreads();
        sel = nsel;
    }
    if (i < N) offs[i] = buf[sel][tid] - v;
    if (tid == 255) bsum[blockIdx.x] = buf[sel][255];
}

__global__ void scan_top(int* __restrict__ bsum, int* __restrict__ offs,
                         int NB, int N) {
    __shared__ int buf[2][512];
    int tid = threadIdx.x;
    int v = (tid < NB) ? bsum[tid] : 0;
    int sel = 0;
    buf[0][tid] = v;
    __syncthreads();
    for (int off = 1; off < 512; off <<= 1) {
        int nsel = sel ^ 1;
        buf[nsel][tid] = buf[sel][tid] + ((tid >= off) ? buf[sel][tid - off] : 0);
        __syncthreads();
        sel = nsel;
    }
    if (tid < NB) bsum[tid] = buf[sel][tid] - v;
    if (tid == 511) offs[N] = buf[sel][511];      // grand total (unused)
}

// ---------------- Kernel 5: binpass — bucket-grouped payload ---------------
// Absolute offset = moffs[i] + bsum[i>>8] (base-add fused).
// pay = rec32<<32 | f32bits(a), rec32 = src<<8 | dst_local.
__global__ __launch_bounds__(1024) void binpass_kernel(
        const float* __restrict__ ew,
        const int* __restrict__ src_idx,
        const int* __restrict__ dst_idx,
        const float* __restrict__ a_src,
        const float* __restrict__ a_dst,
        const int* __restrict__ moffs,
        const int* __restrict__ bsum,
        unsigned long long* __restrict__ pay,
        int E, int N, int K) {
    __shared__ int lcur[KMAX];
    int tid = threadIdx.x;
    for (int j = tid; j < K; j += blockDim.x) {
        int i = j * NBIN + blockIdx.x;
        lcur[j] = moffs[i] + bsum[i >> 8];
    }
    __syncthreads();
    for (int base = blockIdx.x * 1024; base < E; base += NBIN * 1024) {
        int e = base + tid;
        if (e < E) {
            unsigned s = (unsigned)src_idx[e];
            unsigned t = (unsigned)dst_idx[e];
            if (s >= (unsigned)N) s = 0;          // guard
            if (t >= (unsigned)N) t = 0;          // guard
            float a = tanhf(a_src[s] + a_dst[t]) * ew[e];
            int bk = (int)(t >> 8);
            int pos = atomicAdd(&lcur[bk], 1);    // LDS cursor, block-local
            unsigned rec = (s << 8) | (t & 255u);
            pay[pos] = ((unsigned long long)rec << 32) |
                       (unsigned long long)__float_as_uint(a);
        }
    }
}

// ---------------- Kernel 6: fused per-bucket sort + gather -----------------
// Stage bucket in LDS, counting-sort an index array (no global writeback),
// then 16 waves gather: per-node 8-deep-unrolled xh row loads, single h write.
__global__ __launch_bounds__(1024) void sort_gather_kernel(
        const __half* __restrict__ xh,
        const float* __restrict__ x32,
        const unsigned long long* __restrict__ pay,
        const int* __restrict__ moffs,
        const int* __restrict__ bsum,
        float* __restrict__ h,
        int N, int K, int E) {
    __shared__ unsigned long long srec[CAP];      // 48 KB
    __shared__ unsigned short sidx[CAP];          // 12 KB
    __shared__ int hcnt[SPAN];
    __shared__ int hoff[2][SPAN];
    __shared__ int lcur[SPAN];
    __shared__ int nstart[SPAN];
    int tid = threadIdx.x;
    int b   = blockIdx.x;
    int i0 = b * NBIN;
    int bstart = moffs[i0] + bsum[i0 >> 8];
    int bend;
    if (b == K - 1) bend = E;
    else { int i1 = (b + 1) * NBIN; bend = moffs[i1] + bsum[i1 >> 8]; }
    int cnt = bend - bstart;

    if (cnt <= CAP) {
        // ---- stage + histogram ----
        if (tid < SPAN) hcnt[tid] = 0;
        __syncthreads();
        for (int i = tid; i < cnt; i += 1024) {
            unsigned long long r = pay[bstart + i];
            srec[i] = r;
            atomicAdd(&hcnt[(int)((r >> 32) & 255u)], 1);
        }
        __syncthreads();
        // ---- inclusive scan of hcnt[256] ----
        int sel = 0;
        if (tid < SPAN) hoff[0][tid] = hcnt[tid];
        __syncthreads();
        for (int off = 1; off < SPAN; off <<= 1) {
            int nsel = sel ^ 1;
            if (tid < SPAN)
                hoff[nsel][tid] = hoff[sel][tid] +
                                  ((tid >= off) ? hoff[sel][tid - off] : 0);
            __syncthreads();
            sel = nsel;
        }
        if (tid < SPAN) {
            int excl = hoff[sel][tid] - hcnt[tid];
            nstart[tid] = excl;
            lcur[tid]   = excl;
        }
        __syncthreads();
        // ---- permute indices only (sidx), srec stays put ----
        for (int i = tid; i < cnt; i += 1024) {
            unsigned long long r = srec[i];
            int d = (int)((r >> 32) & 255u);
            int pos = atomicAdd(&lcur[d], 1);
            sidx[pos] = (unsigned short)i;
        }
        __syncthreads();
        // ---- gather phase: wave per node, 8-deep unroll ----
        int lane = tid & 63;
        int wave = tid >> 6;                      // 16 waves
        for (int d = wave; d < SPAN; d += 16) {
            int node = b * SPAN + d;
            if (node >= N) break;                 // only last bucket; d monotone
            int p  = nstart[d];
            int pe = p + hcnt[d];
            float a0 = 0.f, a1 = 0.f, a2 = 0.f, a3 = 0.f;
            while (p + 8 <= pe) {
                unsigned long long r0 = srec[sidx[p]];
                unsigned long long r1 = srec[sidx[p + 1]];
                unsigned long long r2 = srec[sidx[p + 2]];
                unsigned long long r3 = srec[sidx[p + 3]];
                unsigned long long r4 = srec[sidx[p + 4]];
                unsigned long long r5 = srec[sidx[p + 5]];
                unsigned long long r6 = srec[sidx[p + 6]];
                unsigned long long r7 = srec[sidx[p + 7]];
                p += 8;
                unsigned s0 = (unsigned)(r0 >> 40); if (s0 >= (unsigned)N) s0 = 0;
                unsigned s1 = (unsigned)(r1 >> 40); if (s1 >= (unsigned)N) s1 = 0;
                unsigned s2 = (unsigned)(r2 >> 40); if (s2 >= (unsigned)N) s2 = 0;
                unsigned s3 = (unsigned)(r3 >> 40); if (s3 >= (unsigned)N) s3 = 0;
                unsigned s4 = (unsigned)(r4 >> 40); if (s4 >= (unsigned)N) s4 = 0;
                unsigned s5 = (unsigned)(r5 >> 40); if (s5 >= (unsigned)N) s5 = 0;
                unsigned s6 = (unsigned)(r6 >> 40); if (s6 >= (unsigned)N) s6 = 0;
                unsigned s7 = (unsigned)(r7 >> 40); if (s7 >= (unsigned)N) s7 = 0;
                float x0 = __half2float(xh[(size_t)s0 * DIM + lane]);
                float x1 = __half2float(xh[(size_t)s1 * DIM + lane]);
                float x2 = __half2float(xh[(size_t)s2 * DIM + lane]);
                float x3 = __half2float(xh[(size_t)s3 * DIM + lane]);
                float x4 = __half2float(xh[(size_t)s4 * DIM + lane]);
                float x5 = __half2float(xh[(size_t)s5 * DIM + lane]);
                float x6 = __half2float(xh[(size_t)s6 * DIM + lane]);
                float x7 = __half2float(xh[(size_t)s7 * DIM + lane]);
                a0 = fmaf(__uint_as_float((unsigned)r0), x0, a0);
                a1 = fmaf(__uint_as_float((unsigned)r1), x1, a1);
                a2 = fmaf(__uint_as_float((unsigned)r2), x2, a2);
                a3 = fmaf(__uint_as_float((unsigned)r3), x3, a3);
                a0 = fmaf(__uint_as_float((unsigned)r4), x4, a0);
                a1 = fmaf(__uint_as_float((unsigned)r5), x5, a1);
                a2 = fmaf(__uint_as_float((unsigned)r6), x6, a2);
                a3 = fmaf(__uint_as_float((unsigned)r7), x7, a3);
            }
            if (p + 4 <= pe) {
                unsigned long long r0 = srec[sidx[p]];
                unsigned long long r1 = srec[sidx[p + 1]];
                unsigned long long r2 = srec[sidx[p + 2]];
                unsigned long long r3 = srec[sidx[p + 3]];
                p += 4;
                unsigned s0 = (unsigned)(r0 >> 40); if (s0 >= (unsigned)N) s0 = 0;
                unsigned s1 = (unsigned)(r1 >> 40); if (s1 >= (unsigned)N) s1 = 0;
                unsigned s2 = (unsigned)(r2 >> 40); if (s2 >= (unsigned)N) s2 = 0;
                unsigned s3 = (unsigned)(r3 >> 40); if (s3 >= (unsigned)N) s3 = 0;
                float x0 = __half2float(xh[(size_t)s0 * DIM + lane]);
                float x1 = __half2float(xh[(size_t)s1 * DIM + lane]);
                float x2 = __half2float(xh[(size_t)s2 * DIM + lane]);
                float x3 = __half2float(xh[(size_t)s3 * DIM + lane]);
                a0 = fmaf(__uint_as_float((unsigned)r0), x0, a0);
                a1 = fmaf(__uint_as_float((unsigned)r1), x1, a1);
                a2 = fmaf(__uint_as_float((unsigned)r2), x2, a2);
                a3 = fmaf(__uint_as_float((unsigned)r3), x3, a3);
            }
            if (p + 2 <= pe) {
                unsigned long long r0 = srec[sidx[p]];
                unsigned long long r1 = srec[sidx[p + 1]];
                p += 2;
                unsigned s0 = (unsigned)(r0 >> 40); if (s0 >= (unsigned)N) s0 = 0;
                unsigned s1 = (unsigned)(r1 >> 40); if (s1 >= (unsigned)N) s1 = 0;
                a0 = fmaf(__uint_as_float((unsigned)r0),
                          __half2float(xh[(size_t)s0 * DIM + lane]), a0);
                a1 = fmaf(__uint_as_float((unsigned)r1),
                          __half2float(xh[(size_t)s1 * DIM + lane]), a1);
            }
            if (p < pe) {
                unsigned long long r0 = srec[sidx[p]];
                unsigned s0 = (unsigned)(r0 >> 40); if (s0 >= (unsigned)N) s0 = 0;
                a0 = fmaf(__uint_as_float((unsigned)r0),
                          __half2float(xh[(size_t)s0 * DIM + lane]), a0);
            }
            h[(size_t)node * DIM + lane] = (a0 + a1) + (a2 + a3);  // deg-0 -> 0
        }
    } else {
        // ---- slow path (cnt > CAP, never for this input): atomic accumulate
        for (int j = tid; j < SPAN * DIM; j += 1024) {
            int node = b * SPAN + (j >> 6);
            if (node < N) h[(size_t)node * DIM + (j & 63)] = 0.f;
        }
        __syncthreads();
        for (int i = tid; i < cnt; i += 1024) {
            unsigned long long r = pay[bstart + i];
            unsigned s = (unsigned)(r >> 40);
            if (s >= (unsigned)N) s = 0;
            int node = b * SPAN + (int)((r >> 32) & 255u);
            float a = __uint_as_float((unsigned)r);
            if (node < N)
                for (int k = 0; k < DIM; ++k)
                    atomicAdd(&h[(size_t)node * DIM + k],
                              a * x32[(size_t)s * DIM + k]);
        }
    }
}

// ---------------- Fallback (round-1 atomic path, known-good) ---------------
__global__ void zero_h_kernel(float* __restrict__ p, int n) {
    int i = blockIdx.x * blockDim.x + threadIdx.x;
    if (i < n) p[i] = 0.f;
}

__global__ void edge_kernel_atomic(const float* __restrict__ x,
                                   const float* __restrict__ ew,
                                   const int* __restrict__ src_idx,
                                   const int* __restrict__ dst_idx,
                                   const float* __restrict__ a_src,
                                   const float* __restrict__ a_dst,
                                   float* __restrict__ h,
                                   int E) {
    int gid  = blockIdx.x * blockDim.x + threadIdx.x;
    int e    = gid >> 6;
    int lane = threadIdx.x & 63;
    if (e >= E) return;
    int s = src_idx[e];
    int t = dst_idx[e];
    float a  = tanhf(a_src[s] + a_dst[t]) * ew[e];
    float xv = x[(size_t)s * DIM + lane];
    atomicAdd(&h[(size_t)t * DIM + lane], a * xv);
}

// Plain score (no xh) for the fallback tier.
__global__ void score_only_kernel(const float* __restrict__ x,
                                  const float* __restrict__ w_src,
                                  const float* __restrict__ w_dst,
                                  float* __restrict__ a_src,
                                  float* __restrict__ a_dst,
                                  int N) {
    int gid  = blockIdx.x * blockDim.x + threadIdx.x;
    int node = gid >> 6;
    int lane = threadIdx.x & 63;
    if (node >= N) return;
    float xv = x[(size_t)node * DIM + lane];
    float s1 = xv * w_src[lane];
    float s2 = xv * w_dst[lane];
    #pragma unroll
    for (int off = 32; off > 0; off >>= 1) {
        s1 += __shfl_down(s1, off, 64);
        s2 += __shfl_down(s2, off, 64);
    }
    if (lane == 0) {
        a_src[node] = s1;
        a_dst[node] = s2;
    }
}

extern "C" void kernel_launch(void* const* d_in, const int* in_sizes, int n_in,
                              void* d_out, int out_size, void* d_ws, size_t ws_size,
                              hipStream_t stream) {
    const float* x     = (const float*)d_in[0];
    const float* w_src = (const float*)d_in[1];
    const float* w_dst = (const float*)d_in[2];
    const float* ew    = (const float*)d_in[3];
    const int*   src   = (const int*)d_in[4];
    const int*   dst   = (const int*)d_in[5];
    float* h = (float*)d_out;

    int N = in_sizes[0] / DIM;
    int E = in_sizes[3];

    int K    = (N + SPAN - 1) / SPAN;     // buckets
    int Ntot = K * NBIN;                  // count-matrix entries
    int NBs  = (Ntot + 255) / 256;        // scan blocks

    // ws layout (4B units):
    // [a_src N][a_dst N][moffs Ntot+1][bsum NBs][pad][pay E*8B][xh N*DIM*2B]
    float* a_src  = (float*)d_ws;
    float* a_dst  = a_src + N;
    int*   moffs  = (int*)(a_dst + N);
    int*   bsum   = moffs + Ntot + 1;
    size_t head_bytes = ((size_t)(2 * N) + (size_t)Ntot + 1 + (size_t)NBs) * 4;
    size_t pay_off = (head_bytes + 15) & ~(size_t)15;
    unsigned long long* pay = (unsigned long long*)((char*)d_ws + pay_off);
    size_t xh_off = pay_off + (size_t)E * 8;
    __half* xh = (__half*)((char*)d_ws + xh_off);
    size_t need = xh_off + (size_t)N * DIM * 2;

    int score_blocks = (N + 3) / 4;

    if (ws_size < need || K > KMAX || NBs > 512 || (N * DIM) % 2 != 0) {
        // fallback: round-1 atomic path
        score_only_kernel<<<score_blocks, 256, 0, stream>>>(x, w_src, w_dst,
                                                            a_src, a_dst, N);
        int ob = (out_size + 255) / 256;
        zero_h_kernel<<<ob, 256, 0, stream>>>(h, out_size);
        int edge_blocks = (E + 3) / 4;
        edge_kernel_atomic<<<edge_blocks, 256, 0, stream>>>(x, ew, src, dst,
                                                            a_src, a_dst, h, E);
        return;
    }

    score_kernel<<<score_blocks, 256, 0, stream>>>(x, w_src, w_dst,
                                                   a_src, a_dst, xh, N);
    hist_coarse<<<NBIN, 1024, 0, stream>>>(dst, moffs, E, N, K);
    scan_part<<<NBs, 256, 0, stream>>>(moffs, moffs, bsum, Ntot);
    scan_top<<<1, 512, 0, stream>>>(bsum, moffs, NBs, Ntot);
    binpass_kernel<<<NBIN, 1024, 0, stream>>>(ew, src, dst, a_src, a_dst,
                                              moffs, bsum, pay, E, N, K);
    sort_gather_kernel<<<K, 1024, 0, stream>>>(xh, x, pay, moffs, bsum,
                                               h, N, K, E);
}